// Round 2
// baseline (484.498 us; speedup 1.0000x reference)
//
#include <hip/hip_runtime.h>

// ---------------------------------------------------------------------------
// GridNet fused forward: MLP (bf16 MFMA) + softmax + 5x5 gather + sigmoid
// B=262144, GS=(1024,2048), NS=5, layers 2-64-256-512-256-64-75
// R2: 1024 threads/block (16 waves) to double occupancy (was 8 waves, 23% occ,
//     all pipes <20% busy => latency/barrier-bound). logitsS aliased into ldsB.
// ---------------------------------------------------------------------------

#define PI_F     3.14159265358979323846f
#define TWO_PI_F 6.28318530717958647692f

typedef __attribute__((ext_vector_type(8))) short bf16x8;   // 8 bf16 = 4 VGPRs
typedef __attribute__((ext_vector_type(4))) float f32x4;    // MFMA C/D frag

__device__ __forceinline__ short f2bf(float f) {
    unsigned u = __builtin_bit_cast(unsigned, f);
    u += 0x7fffu + ((u >> 16) & 1u);            // round-nearest-even
    return (short)(u >> 16);
}

// ws layout (in shorts):
//  Wt2 [256][64]   @ 0
//  Wt3 [512][256]  @ 16384
//  Wt4 [256][512]  @ 147456
//  Wt5 [64][256]   @ 278528
//  Wt6 [80][64]    @ 294912   (rows 75..79 zero-padded)
//  b6pad 80 floats @ 300032   (entries 75..79 = 0)
#define WT2_OFF 0
#define WT3_OFF 16384
#define WT4_OFF 147456
#define WT5_OFF 278528
#define WT6_OFF 294912
#define B6_OFF  300032
#define PREP_TOTAL (300032 + 80)

__global__ void prep_weights(const float* __restrict__ w2, const float* __restrict__ w3,
                             const float* __restrict__ w4, const float* __restrict__ w5,
                             const float* __restrict__ w6, const float* __restrict__ b6,
                             short* __restrict__ ws) {
    int idx = blockIdx.x * blockDim.x + threadIdx.x;
    if (idx >= PREP_TOTAL) return;
    if (idx >= 300032) {                         // padded bias6 as float
        int n = idx - 300032;
        ((float*)(ws + B6_OFF))[n] = (n < 75) ? b6[n] : 0.0f;
        return;
    }
    float v;
    if (idx < WT3_OFF) {        // Wt2: [n<256][k<64] <- w2[k][n] (64x256)
        int i = idx - WT2_OFF; int n = i >> 6, k = i & 63;
        v = w2[k * 256 + n];
    } else if (idx < WT4_OFF) { // Wt3: [n<512][k<256] <- w3[k][n] (256x512)
        int i = idx - WT3_OFF; int n = i >> 8, k = i & 255;
        v = w3[k * 512 + n];
    } else if (idx < WT5_OFF) { // Wt4: [n<256][k<512] <- w4[k][n] (512x256)
        int i = idx - WT5_OFF ? idx - WT4_OFF : idx - WT4_OFF; int n = i >> 9, k = i & 511;
        v = w4[k * 256 + n];
    } else if (idx < WT6_OFF) { // Wt5: [n<64][k<256] <- w5[k][n] (256x64)
        int i = idx - WT5_OFF; int n = i >> 8, k = i & 255;
        v = w5[k * 64 + n];
    } else {                    // Wt6: [n<80][k<64] <- w6[k][n] (64x75), zero pad
        int i = idx - WT6_OFF; int n = i >> 6, k = i & 63;
        v = (n < 75) ? w6[k * 75 + n] : 0.0f;
    }
    ws[idx] = f2bf(v);
}

// One MFMA layer: out[m][n] = act(in[m][:] @ W + b),  W given transposed [N][K] bf16.
// Mtile = 64 rows in LDS. 16 waves split as MG m-groups x NG n-groups.
// A-frag: lane holds A[m=lane&15][k=(lane>>4)*8+j] -> ds_read_b128 from LDS (stride sIn).
// B-frag: lane holds B[k=(lane>>4)*8+j][n=lane&15] -> global 16B load from Wt[n][k].
// D: col = lane&15, row = (lane>>4)*4 + reg.
template<int K, int N, int MG, int NG, bool RELU, bool OUTF32>
__device__ __forceinline__ void mlp_layer(const short* __restrict__ aIn, const int sIn,
                                          void* outP, const int sOut,
                                          const short* __restrict__ Wt,
                                          const float* __restrict__ bias,
                                          int wave, int lane) {
    constexpr int MT = 4 / MG;          // 16-row m-tiles per wave
    constexpr int NT = (N / 16) / NG;   // 16-col n-tiles per wave
    if (wave >= MG * NG) return;
    const int mg = wave / NG, ng = wave % NG;
    const int mb = mg * MT * 16, nb = ng * NT * 16;
    const int lr = lane & 15, lq = lane >> 4;

    f32x4 acc[MT][NT];
    #pragma unroll
    for (int j = 0; j < NT; ++j) {
        float bv = bias[nb + j * 16 + lr];
        #pragma unroll
        for (int i = 0; i < MT; ++i) { acc[i][j] = (f32x4){bv, bv, bv, bv}; }
    }

    #pragma unroll
    for (int k0 = 0; k0 < K; k0 += 32) {
        bf16x8 a[MT], b[NT];
        #pragma unroll
        for (int i = 0; i < MT; ++i)
            a[i] = *(const bf16x8*)(aIn + (mb + i * 16 + lr) * sIn + k0 + lq * 8);
        #pragma unroll
        for (int j = 0; j < NT; ++j)
            b[j] = *(const bf16x8*)(Wt + (nb + j * 16 + lr) * K + k0 + lq * 8);
        #pragma unroll
        for (int i = 0; i < MT; ++i) {
            #pragma unroll
            for (int j = 0; j < NT; ++j)
                acc[i][j] = __builtin_amdgcn_mfma_f32_16x16x32_bf16(a[i], b[j], acc[i][j], 0, 0, 0);
        }
    }

    #pragma unroll
    for (int i = 0; i < MT; ++i) {
        #pragma unroll
        for (int j = 0; j < NT; ++j) {
            const int col  = nb + j * 16 + lr;
            const int rowb = mb + i * 16 + lq * 4;
            #pragma unroll
            for (int r = 0; r < 4; ++r) {
                float v = acc[i][j][r];
                if (RELU) v = fmaxf(v, 0.0f);
                if (OUTF32) ((float*)outP)[(rowb + r) * sOut + col] = v;
                else        ((short*)outP)[(rowb + r) * sOut + col] = f2bf(v);
            }
        }
    }
}

__global__ __launch_bounds__(1024, 4) void gridnet_fused(
    const float* __restrict__ pos, const float* __restrict__ grid_pos,
    const float* __restrict__ w1, const float* __restrict__ b1,
    const float* __restrict__ b2, const float* __restrict__ b3,
    const float* __restrict__ b4, const float* __restrict__ b5,
    const short* __restrict__ ws, float* __restrict__ out) {

    __shared__ short ldsA[64 * 520];     // 66560 B: h1(72), h3(520), h5(72)
    __shared__ short ldsB[64 * 264];     // 33792 B: h2(264), h4(264), logits alias
    __shared__ float posS[64 * 2];
    float* logitsS = (float*)ldsB;       // 64*80 f32 = 20480 B <= 33792 B (h4 dead)

    const int tid  = threadIdx.x;
    const int wave = tid >> 6;
    const int lane = tid & 63;
    const int m0   = blockIdx.x * 64;

    if (tid < 128) posS[tid] = pos[m0 * 2 + tid];
    __syncthreads();

    // ---- layer 1 (2 -> 64), VALU ----
    #pragma unroll
    for (int r = 0; r < 4; ++r) {
        int idx = tid + r * 1024;         // 64 pts x 64 outs
        int m = idx >> 6, n = idx & 63;
        float v = posS[m * 2 + 0] * w1[n] + posS[m * 2 + 1] * w1[64 + n] + b1[n];
        ldsA[m * 72 + n] = f2bf(fmaxf(v, 0.0f));
    }
    __syncthreads();

    mlp_layer< 64, 256, 1, 16, true,  false>(ldsA,  72, ldsB, 264, ws + WT2_OFF, b2, wave, lane);
    __syncthreads();
    mlp_layer<256, 512, 1, 16, true,  false>(ldsB, 264, ldsA, 520, ws + WT3_OFF, b3, wave, lane);
    __syncthreads();
    mlp_layer<512, 256, 1, 16, true,  false>(ldsA, 520, ldsB, 264, ws + WT4_OFF, b4, wave, lane);
    __syncthreads();
    mlp_layer<256,  64, 4,  4, true,  false>(ldsB, 264, ldsA,  72, ws + WT5_OFF, b5, wave, lane);
    __syncthreads();
    mlp_layer< 64,  80, 2,  5, false, true >(ldsA,  72, logitsS, 80, ws + WT6_OFF,
                                             (const float*)(ws + B6_OFF), wave, lane);
    __syncthreads();

    // ---- epilogue: softmax(75) + 5x5x3 gather + sigmoid, 16 lanes per point ----
    const int p = tid >> 4;              // point within tile
    const int s = tid & 15;              // sub-lane
    const float p0 = posS[p * 2 + 0], p1 = posS[p * 2 + 1];
    const int tx0 = (int)(p0 / PI_F * 1023.0f);                 // == int(gx), ix = tx0 + dy
    const int ty0 = (int)((p1 + PI_F) / TWO_PI_F * 2047.0f);    // == int(gy), iy = ty0 + dx

    const float* lrow = logitsS + p * 80;
    float lv[5];
    float mx = -1e30f;
    #pragma unroll
    for (int i = 0; i < 5; ++i) {
        int f = s + i * 16;
        float v = (f < 75) ? lrow[f] : -1e30f;
        lv[i] = v;
        mx = fmaxf(mx, v);
    }
    mx = fmaxf(mx, __shfl_xor(mx, 1, 16));
    mx = fmaxf(mx, __shfl_xor(mx, 2, 16));
    mx = fmaxf(mx, __shfl_xor(mx, 4, 16));
    mx = fmaxf(mx, __shfl_xor(mx, 8, 16));

    float den = 0.0f, x0 = 0.0f, x1 = 0.0f, x2 = 0.0f;
    #pragma unroll
    for (int i = 0; i < 5; ++i) {
        int f = s + i * 16;
        if (f < 75) {
            float e = __expf(lv[i] - mx);
            den += e;
            int c = f / 25, rr = f % 25, dy = rr / 5, dx = rr % 5;
            float g = grid_pos[((tx0 + dy) * 2052 + (ty0 + dx)) * 3 + c];
            if      (c == 0) x0 += e * g;
            else if (c == 1) x1 += e * g;
            else             x2 += e * g;
        }
    }
    #pragma unroll
    for (int mask = 1; mask < 16; mask <<= 1) {
        den += __shfl_xor(den, mask, 16);
        x0  += __shfl_xor(x0,  mask, 16);
        x1  += __shfl_xor(x1,  mask, 16);
        x2  += __shfl_xor(x2,  mask, 16);
    }
    if (s < 3) {
        float xv = (s == 0) ? x0 : (s == 1 ? x1 : x2);
        xv /= den;
        float sig = 1.0f / (1.0f + __expf(-xv));
        out[(m0 + p) * 3 + s] = (sig > 0.1f) ? sig * 255.0f : 0.0f;
    }
}

extern "C" void kernel_launch(void* const* d_in, const int* in_sizes, int n_in,
                              void* d_out, int out_size, void* d_ws, size_t ws_size,
                              hipStream_t stream) {
    const float* pos      = (const float*)d_in[0];
    const float* grid_pos = (const float*)d_in[1];
    const float* w1 = (const float*)d_in[2];
    const float* b1 = (const float*)d_in[3];
    const float* w2 = (const float*)d_in[4];
    const float* b2 = (const float*)d_in[5];
    const float* w3 = (const float*)d_in[6];
    const float* b3 = (const float*)d_in[7];
    const float* w4 = (const float*)d_in[8];
    const float* b4 = (const float*)d_in[9];
    const float* w5 = (const float*)d_in[10];
    const float* b5 = (const float*)d_in[11];
    const float* w6 = (const float*)d_in[12];
    const float* b6 = (const float*)d_in[13];
    short* ws = (short*)d_ws;
    float* out = (float*)d_out;

    prep_weights<<<(PREP_TOTAL + 255) / 256, 256, 0, stream>>>(w2, w3, w4, w5, w6, b6, ws);
    gridnet_fused<<<262144 / 64, 1024, 0, stream>>>(pos, grid_pos, w1, b1, b2, b3, b4, b5, ws, out);
}

// Round 3
// 323.338 us; speedup vs baseline: 1.4984x; 1.4984x over previous
//
#include <hip/hip_runtime.h>

// ---------------------------------------------------------------------------
// GridNet fused forward: MLP (bf16 MFMA) + softmax + 5x5 gather + sigmoid
// B=262144, GS=(1024,2048), NS=5, layers 2-64-256-512-256-64-75
// R3: role-swapped MFMA (weights=A, acts=B) -> packed b64 activation writes;
//     fragment-packed weights (coalesced 1024B wave loads); 8 waves with
//     MT x NT register blocking + k-prefetch (launch_bounds 512,2 -> 256 VGPR).
// ---------------------------------------------------------------------------

#define PI_F     3.14159265358979323846f
#define TWO_PI_F 6.28318530717958647692f

typedef __attribute__((ext_vector_type(8))) short bf16x8;   // 8 bf16 = 4 VGPRs
typedef __attribute__((ext_vector_type(4))) short bf16x4;   // 8 B packed
typedef __attribute__((ext_vector_type(4))) float f32x4;    // MFMA C/D frag

__device__ __forceinline__ short f2bf(float f) {
    unsigned u = __builtin_bit_cast(unsigned, f);
    u += 0x7fffu + ((u >> 16) & 1u);            // round-nearest-even
    return (short)(u >> 16);
}

// ws layout (shorts). Weights stored fragment-packed for MFMA A-operand:
//   frag f = ot*KT + kt (ot = 16-wide outdim tile, kt = 32-deep k tile),
//   within frag: lane*8 + e  <->  W[k = kt*32 + (lane>>4)*8 + e][n = ot*16 + (lane&15)]
// L2: 64x256 (KT=2,  OT=16) @ 0       (16384)
// L3: 256x512(KT=8,  OT=32) @ 16384   (131072)
// L4: 512x256(KT=16, OT=16) @ 147456  (131072)
// L5: 256x64 (KT=8,  OT=4)  @ 278528  (16384)
// L6: 64x80  (KT=2,  OT=5)  @ 294912  (5120, cols 75..79 zeroed)
// b6pad: 80 f32 @ short-offset 300032
#define P2_OFF 0
#define P3_OFF 16384
#define P4_OFF 147456
#define P5_OFF 278528
#define P6_OFF 294912
#define B6_OFF 300032
#define PREP_W_TOTAL 300032
#define PREP_TOTAL (PREP_W_TOTAL + 80)

__global__ void prep_weights(const float* __restrict__ w2, const float* __restrict__ w3,
                             const float* __restrict__ w4, const float* __restrict__ w5,
                             const float* __restrict__ w6, const float* __restrict__ b6,
                             short* __restrict__ ws) {
    int idx = blockIdx.x * blockDim.x + threadIdx.x;
    if (idx >= PREP_TOTAL) return;
    if (idx >= PREP_W_TOTAL) {                   // padded bias6 as float
        int n = idx - PREP_W_TOTAL;
        ((float*)(ws + B6_OFF))[n] = (n < 75) ? b6[n] : 0.0f;
        return;
    }
    int rel, KT, N;
    const float* W;
    if (idx < P3_OFF)      { rel = idx - P2_OFF; KT = 2;  N = 256; W = w2; }
    else if (idx < P4_OFF) { rel = idx - P3_OFF; KT = 8;  N = 512; W = w3; }
    else if (idx < P5_OFF) { rel = idx - P4_OFF; KT = 16; N = 256; W = w4; }
    else if (idx < P6_OFF) { rel = idx - P5_OFF; KT = 8;  N = 64;  W = w5; }
    else                   { rel = idx - P6_OFF; KT = 2;  N = 80;  W = w6; }
    int f = rel >> 9, r = rel & 511, lane = r >> 3, e = r & 7;
    int kt = f % KT, ot = f / KT;
    int n = ot * 16 + (lane & 15);
    int k = kt * 32 + (lane >> 4) * 8 + e;
    float v;
    if (N == 80) v = (n < 75) ? w6[k * 75 + n] : 0.0f;   // true row stride 75
    else         v = W[k * N + n];
    ws[idx] = f2bf(v);
}

// Role-swapped layer: D[od][pt] = sum_k W^T[od][k] * act[k][pt] (+bias[od])
//  A (weights, fragment-packed, global/L2): lane -> A[od=lane&15][k=(lane>>4)*8+j]
//  B (acts in LDS, [pt][dim], stride sIn):  lane -> B[k=(lane>>4)*8+j][pt=lane&15]
//  D: pt = lane&15, od = (lane>>4)*4 + r  -> 4 contiguous dims => b64 packed write.
// 8 waves split into (ODT/MT) od-groups x (4/NT) pt-groups.
template<int K, int ODT, int MT, int NT, bool RELU, bool OUTF32>
__device__ __forceinline__ void mlp_layer(const short* __restrict__ act, const int sIn,
                                          void* __restrict__ outP, const int sOut,
                                          const short* __restrict__ pack,
                                          const float* __restrict__ bias,
                                          const int wave, const int lane) {
    constexpr int PTG = 4 / NT;          // point groups
    constexpr int OG  = ODT / MT;        // od groups
    constexpr int KT  = K / 32;
    const int og = wave / PTG;
    if (og >= OG) return;
    const int ptb = (wave % PTG) * (NT * 16);
    const int otb = og * MT;
    const int lr = lane & 15, lq = lane >> 4;

    f32x4 acc[MT][NT];
    #pragma unroll
    for (int i = 0; i < MT; ++i) {
        f32x4 bv = *(const f32x4*)(bias + (otb + i) * 16 + lq * 4);
        #pragma unroll
        for (int j = 0; j < NT; ++j) acc[i][j] = bv;
    }

    const short* ap = pack + ((otb * KT) << 9) + (lane << 3);
    const short* bp = act + (ptb + lr) * sIn + lq * 8;

    bf16x8 a[MT], b[NT];
    #pragma unroll
    for (int i = 0; i < MT; ++i) a[i] = *(const bf16x8*)(ap + ((i * KT) << 9));
    #pragma unroll
    for (int j = 0; j < NT; ++j) b[j] = *(const bf16x8*)(bp + j * 16 * sIn);

    #pragma unroll
    for (int kt = 0; kt < KT - 1; ++kt) {
        bf16x8 a2[MT], b2[NT];
        #pragma unroll
        for (int i = 0; i < MT; ++i) a2[i] = *(const bf16x8*)(ap + ((i * KT + kt + 1) << 9));
        #pragma unroll
        for (int j = 0; j < NT; ++j) b2[j] = *(const bf16x8*)(bp + j * 16 * sIn + (kt + 1) * 32);
        #pragma unroll
        for (int i = 0; i < MT; ++i) {
            #pragma unroll
            for (int j = 0; j < NT; ++j)
                acc[i][j] = __builtin_amdgcn_mfma_f32_16x16x32_bf16(a[i], b[j], acc[i][j], 0, 0, 0);
        }
        #pragma unroll
        for (int i = 0; i < MT; ++i) a[i] = a2[i];
        #pragma unroll
        for (int j = 0; j < NT; ++j) b[j] = b2[j];
    }
    #pragma unroll
    for (int i = 0; i < MT; ++i) {
        #pragma unroll
        for (int j = 0; j < NT; ++j)
            acc[i][j] = __builtin_amdgcn_mfma_f32_16x16x32_bf16(a[i], b[j], acc[i][j], 0, 0, 0);
    }

    #pragma unroll
    for (int i = 0; i < MT; ++i) {
        #pragma unroll
        for (int j = 0; j < NT; ++j) {
            const int row = ptb + j * 16 + lr;          // point
            const int col = (otb + i) * 16 + lq * 4;    // output dim (4 contiguous)
            if (OUTF32) {
                *(f32x4*)((float*)outP + row * sOut + col) = acc[i][j];
            } else {
                f32x4 v = acc[i][j];
                if (RELU) {
                    v[0] = fmaxf(v[0], 0.0f); v[1] = fmaxf(v[1], 0.0f);
                    v[2] = fmaxf(v[2], 0.0f); v[3] = fmaxf(v[3], 0.0f);
                }
                bf16x4 pk = (bf16x4){ f2bf(v[0]), f2bf(v[1]), f2bf(v[2]), f2bf(v[3]) };
                *(bf16x4*)((short*)outP + row * sOut + col) = pk;
            }
        }
    }
}

__global__ __launch_bounds__(512, 2) void gridnet_fused(
    const float* __restrict__ pos, const float* __restrict__ grid_pos,
    const float* __restrict__ w1, const float* __restrict__ b1,
    const float* __restrict__ b2, const float* __restrict__ b3,
    const float* __restrict__ b4, const float* __restrict__ b5,
    const short* __restrict__ ws, float* __restrict__ out) {

    __shared__ short ldsA[64 * 520];     // 66560 B: h1(72), h3(520), h5(72)
    __shared__ short ldsB[64 * 264];     // 33792 B: h2(264), h4(264), logits alias
    __shared__ float posS[128];
    float* logitsS = (float*)ldsB;       // 64*80 f32 = 20480 B (h4 dead by L6)

    const int tid  = threadIdx.x;
    const int wave = tid >> 6;
    const int lane = tid & 63;
    const int m0   = blockIdx.x * 64;

    if (tid < 128) posS[tid] = pos[m0 * 2 + tid];
    __syncthreads();

    // ---- layer 1 (2 -> 64), VALU; h1 stored [pt][dim] stride 72 ----
    #pragma unroll
    for (int r = 0; r < 8; ++r) {
        int idx = tid + r * 512;          // 64 pts x 64 dims
        int m = idx >> 6, n = idx & 63;
        float v = fmaf(posS[m * 2 + 0], w1[n], fmaf(posS[m * 2 + 1], w1[64 + n], b1[n]));
        ldsA[m * 72 + n] = f2bf(fmaxf(v, 0.0f));
    }
    __syncthreads();

    mlp_layer< 64, 16, 2, 4, true,  false>(ldsA,  72, ldsB, 264, ws + P2_OFF, b2, wave, lane);
    __syncthreads();
    mlp_layer<256, 32, 4, 4, true,  false>(ldsB, 264, ldsA, 520, ws + P3_OFF, b3, wave, lane);
    __syncthreads();
    mlp_layer<512, 16, 2, 4, true,  false>(ldsA, 520, ldsB, 264, ws + P4_OFF, b4, wave, lane);
    __syncthreads();
    mlp_layer<256,  4, 1, 2, true,  false>(ldsB, 264, ldsA,  72, ws + P5_OFF, b5, wave, lane);
    __syncthreads();
    mlp_layer< 64,  5, 1, 4, false, true >(ldsA,  72, logitsS, 80, ws + P6_OFF,
                                           (const float*)(ws + B6_OFF), wave, lane);
    __syncthreads();

    // ---- epilogue: softmax(75) + 5x5x3 gather + sigmoid, 8 lanes per point ----
    const int p = tid >> 3;              // point within tile
    const int s = tid & 7;               // sub-lane
    const float p0 = posS[p * 2 + 0], p1 = posS[p * 2 + 1];
    const int tx0 = (int)(p0 / PI_F * 1023.0f);                 // == int(gx), ix = tx0 + dy
    const int ty0 = (int)((p1 + PI_F) / TWO_PI_F * 2047.0f);    // == int(gy), iy = ty0 + dx

    const float* lrow = logitsS + p * 80;
    float lv[10];
    float mx = -1e30f;
    #pragma unroll
    for (int i = 0; i < 10; ++i) {
        int f = s + i * 8;
        float v = (f < 75) ? lrow[f] : -1e30f;
        lv[i] = v;
        mx = fmaxf(mx, v);
    }
    mx = fmaxf(mx, __shfl_xor(mx, 1, 8));
    mx = fmaxf(mx, __shfl_xor(mx, 2, 8));
    mx = fmaxf(mx, __shfl_xor(mx, 4, 8));

    float den = 0.0f, x0 = 0.0f, x1 = 0.0f, x2 = 0.0f;
    #pragma unroll
    for (int i = 0; i < 10; ++i) {
        int f = s + i * 8;
        if (f < 75) {
            float e = __expf(lv[i] - mx);
            den += e;
            int c = f / 25, rr = f % 25, dy = rr / 5, dx = rr % 5;
            float g = grid_pos[((tx0 + dy) * 2052 + (ty0 + dx)) * 3 + c];
            if      (c == 0) x0 += e * g;
            else if (c == 1) x1 += e * g;
            else             x2 += e * g;
        }
    }
    #pragma unroll
    for (int mask = 1; mask < 8; mask <<= 1) {
        den += __shfl_xor(den, mask, 8);
        x0  += __shfl_xor(x0,  mask, 8);
        x1  += __shfl_xor(x1,  mask, 8);
        x2  += __shfl_xor(x2,  mask, 8);
    }
    if (s < 3) {
        float xv = (s == 0) ? x0 : (s == 1 ? x1 : x2);
        xv /= den;
        float sig = 1.0f / (1.0f + __expf(-xv));
        out[(m0 + p) * 3 + s] = (sig > 0.1f) ? sig * 255.0f : 0.0f;
    }
}

extern "C" void kernel_launch(void* const* d_in, const int* in_sizes, int n_in,
                              void* d_out, int out_size, void* d_ws, size_t ws_size,
                              hipStream_t stream) {
    const float* pos      = (const float*)d_in[0];
    const float* grid_pos = (const float*)d_in[1];
    const float* w1 = (const float*)d_in[2];
    const float* b1 = (const float*)d_in[3];
    const float* w2 = (const float*)d_in[4];
    const float* b2 = (const float*)d_in[5];
    const float* w3 = (const float*)d_in[6];
    const float* b3 = (const float*)d_in[7];
    const float* w4 = (const float*)d_in[8];
    const float* b4 = (const float*)d_in[9];
    const float* w5 = (const float*)d_in[10];
    const float* b5 = (const float*)d_in[11];
    const float* w6 = (const float*)d_in[12];
    const float* b6 = (const float*)d_in[13];
    short* ws = (short*)d_ws;
    float* out = (float*)d_out;

    prep_weights<<<(PREP_TOTAL + 255) / 256, 256, 0, stream>>>(w2, w3, w4, w5, w6, b6, ws);
    gridnet_fused<<<262144 / 64, 512, 0, stream>>>(pos, grid_pos, w1, b1, b2, b3, b4, b5, ws, out);
}

// Round 4
// 267.588 us; speedup vs baseline: 1.8106x; 1.2083x over previous
//
#include <hip/hip_runtime.h>

// ---------------------------------------------------------------------------
// GridNet fused forward: MLP (bf16 MFMA) + softmax + 5x5 gather + sigmoid
// B=262144, GS=(1024,2048), NS=5, layers 2-64-256-512-256-64-75
// R4: split L3/L4 into 256-wide halves so peak LDS = 75.5 KB -> 2 blocks/CU
//     (R3 was 100.8 KB -> 1 block/CU, 22% occupancy, barrier-drain bound).
//     L4 partial acc lives in VGPRs across L3b; launch_bounds(512,4) caps 128.
// ---------------------------------------------------------------------------

#define PI_F     3.14159265358979323846f
#define TWO_PI_F 6.28318530717958647692f

typedef __attribute__((ext_vector_type(8))) short bf16x8;   // 8 bf16 = 4 VGPRs
typedef __attribute__((ext_vector_type(4))) short bf16x4;   // 8 B packed
typedef __attribute__((ext_vector_type(4))) float f32x4;    // MFMA C/D frag

__device__ __forceinline__ short f2bf(float f) {
    unsigned u = __builtin_bit_cast(unsigned, f);
    u += 0x7fffu + ((u >> 16) & 1u);            // round-nearest-even
    return (short)(u >> 16);
}

// ws layout (shorts). Weights stored fragment-packed for MFMA A-operand:
//   frag f = ot*KT + kt (ot = 16-wide outdim tile, kt = 32-deep k tile),
//   within frag: lane*8 + e  <->  W[k = kt*32 + (lane>>4)*8 + e][n = ot*16 + (lane&15)]
// L2: 64x256 (KT=2,  OT=16) @ 0       (16384)
// L3: 256x512(KT=8,  OT=32) @ 16384   (131072)
// L4: 512x256(KT=16, OT=16) @ 147456  (131072)
// L5: 256x64 (KT=8,  OT=4)  @ 278528  (16384)
// L6: 64x80  (KT=2,  OT=5)  @ 294912  (5120, cols 75..79 zeroed)
// b6pad: 80 f32 @ short-offset 300032
#define P2_OFF 0
#define P3_OFF 16384
#define P4_OFF 147456
#define P5_OFF 278528
#define P6_OFF 294912
#define B6_OFF 300032
#define PREP_W_TOTAL 300032
#define PREP_TOTAL (PREP_W_TOTAL + 80)

__global__ void prep_weights(const float* __restrict__ w2, const float* __restrict__ w3,
                             const float* __restrict__ w4, const float* __restrict__ w5,
                             const float* __restrict__ w6, const float* __restrict__ b6,
                             short* __restrict__ ws) {
    int idx = blockIdx.x * blockDim.x + threadIdx.x;
    if (idx >= PREP_TOTAL) return;
    if (idx >= PREP_W_TOTAL) {                   // padded bias6 as float
        int n = idx - PREP_W_TOTAL;
        ((float*)(ws + B6_OFF))[n] = (n < 75) ? b6[n] : 0.0f;
        return;
    }
    int rel, KT, N;
    const float* W;
    if (idx < P3_OFF)      { rel = idx - P2_OFF; KT = 2;  N = 256; W = w2; }
    else if (idx < P4_OFF) { rel = idx - P3_OFF; KT = 8;  N = 512; W = w3; }
    else if (idx < P5_OFF) { rel = idx - P4_OFF; KT = 16; N = 256; W = w4; }
    else if (idx < P6_OFF) { rel = idx - P5_OFF; KT = 8;  N = 64;  W = w5; }
    else                   { rel = idx - P6_OFF; KT = 2;  N = 80;  W = w6; }
    int f = rel >> 9, r = rel & 511, lane = r >> 3, e = r & 7;
    int kt = f % KT, ot = f / KT;
    int n = ot * 16 + (lane & 15);
    int k = kt * 32 + (lane >> 4) * 8 + e;
    float v;
    if (N == 80) v = (n < 75) ? w6[k * 75 + n] : 0.0f;   // true row stride 75
    else         v = W[k * N + n];
    ws[idx] = f2bf(v);
}

// Role-swapped layer: D[od][pt] = sum_k W^T[od][k] * act[k][pt] (+bias[od])
//  A (weights, fragment-packed, global/L2): lane -> A[od=lane&15][k=(lane>>4)*8+j]
//  B (acts in LDS, [pt][dim], stride sIn):  lane -> B[k=(lane>>4)*8+j][pt=lane&15]
//  D: pt = lane&15, od = (lane>>4)*4 + r  -> 4 contiguous dims => b64 packed write.
// 8 waves split into (ODT/MT) od-groups x (4/NT) pt-groups.
// KTS = k-tiles per ot in the packed layout; KT0 = starting k-tile (split layers).
// INIT: bias-init acc. STORE: write result. PF: k-loop prefetch.
template<int K, int ODT, int MT, int NT, int KTS, int KT0,
         bool RELU, bool OUTF32, bool INIT, bool STORE, bool PF>
__device__ __forceinline__ void mlp_layer(f32x4 (&acc)[MT][NT],
                                          const short* __restrict__ act, const int sIn,
                                          void* __restrict__ outP, const int sOut,
                                          const short* __restrict__ pack,
                                          const float* __restrict__ bias,
                                          const int wave, const int lane) {
    constexpr int PTG = 4 / NT;          // point groups
    constexpr int OG  = ODT / MT;        // od groups
    constexpr int KT  = K / 32;          // k-tiles this pass
    const int og = wave / PTG;
    if (og >= OG) return;
    const int ptb = (wave % PTG) * (NT * 16);
    const int otb = og * MT;
    const int lr = lane & 15, lq = lane >> 4;

    if (INIT) {
        #pragma unroll
        for (int i = 0; i < MT; ++i) {
            f32x4 bv = *(const f32x4*)(bias + (otb + i) * 16 + lq * 4);
            #pragma unroll
            for (int j = 0; j < NT; ++j) acc[i][j] = bv;
        }
    }

    const short* ap = pack + ((otb * KTS + KT0) << 9) + (lane << 3);
    const short* bp = act + (ptb + lr) * sIn + lq * 8;

    if (PF) {
        bf16x8 a[MT], b[NT];
        #pragma unroll
        for (int i = 0; i < MT; ++i) a[i] = *(const bf16x8*)(ap + ((i * KTS) << 9));
        #pragma unroll
        for (int j = 0; j < NT; ++j) b[j] = *(const bf16x8*)(bp + j * 16 * sIn);

        #pragma unroll
        for (int kt = 0; kt < KT - 1; ++kt) {
            bf16x8 a2[MT], b2[NT];
            #pragma unroll
            for (int i = 0; i < MT; ++i) a2[i] = *(const bf16x8*)(ap + ((i * KTS + kt + 1) << 9));
            #pragma unroll
            for (int j = 0; j < NT; ++j) b2[j] = *(const bf16x8*)(bp + j * 16 * sIn + (kt + 1) * 32);
            #pragma unroll
            for (int i = 0; i < MT; ++i) {
                #pragma unroll
                for (int j = 0; j < NT; ++j)
                    acc[i][j] = __builtin_amdgcn_mfma_f32_16x16x32_bf16(a[i], b[j], acc[i][j], 0, 0, 0);
            }
            #pragma unroll
            for (int i = 0; i < MT; ++i) a[i] = a2[i];
            #pragma unroll
            for (int j = 0; j < NT; ++j) b[j] = b2[j];
        }
        #pragma unroll
        for (int i = 0; i < MT; ++i) {
            #pragma unroll
            for (int j = 0; j < NT; ++j)
                acc[i][j] = __builtin_amdgcn_mfma_f32_16x16x32_bf16(a[i], b[j], acc[i][j], 0, 0, 0);
        }
    } else {
        #pragma unroll
        for (int kt = 0; kt < KT; ++kt) {
            bf16x8 a[MT], b[NT];
            #pragma unroll
            for (int i = 0; i < MT; ++i) a[i] = *(const bf16x8*)(ap + ((i * KTS + kt) << 9));
            #pragma unroll
            for (int j = 0; j < NT; ++j) b[j] = *(const bf16x8*)(bp + j * 16 * sIn + kt * 32);
            #pragma unroll
            for (int i = 0; i < MT; ++i) {
                #pragma unroll
                for (int j = 0; j < NT; ++j)
                    acc[i][j] = __builtin_amdgcn_mfma_f32_16x16x32_bf16(a[i], b[j], acc[i][j], 0, 0, 0);
            }
        }
    }

    if (STORE) {
        #pragma unroll
        for (int i = 0; i < MT; ++i) {
            #pragma unroll
            for (int j = 0; j < NT; ++j) {
                const int row = ptb + j * 16 + lr;          // point
                const int col = (otb + i) * 16 + lq * 4;    // output dim (4 contiguous)
                if (OUTF32) {
                    *(f32x4*)((float*)outP + row * sOut + col) = acc[i][j];
                } else {
                    f32x4 v = acc[i][j];
                    if (RELU) {
                        v[0] = fmaxf(v[0], 0.0f); v[1] = fmaxf(v[1], 0.0f);
                        v[2] = fmaxf(v[2], 0.0f); v[3] = fmaxf(v[3], 0.0f);
                    }
                    bf16x4 pk = (bf16x4){ f2bf(v[0]), f2bf(v[1]), f2bf(v[2]), f2bf(v[3]) };
                    *(bf16x4*)((short*)outP + row * sOut + col) = pk;
                }
            }
        }
    }
}

__global__ __launch_bounds__(512, 4) void gridnet_fused(
    const float* __restrict__ pos, const float* __restrict__ grid_pos,
    const float* __restrict__ w1, const float* __restrict__ b1,
    const float* __restrict__ b2, const float* __restrict__ b3,
    const float* __restrict__ b4, const float* __restrict__ b5,
    const short* __restrict__ ws, float* __restrict__ out) {

    // region1: h2, then h4.   region2: h3a/h3b, then logits (f32).
    // region3: h1, then h5.   Peak LDS = 33792+33792+9216+512 = 77312 B -> 2 blk/CU.
    __shared__ short region1[64 * 264];
    __shared__ short region2[64 * 264];
    __shared__ short region3[64 * 72];
    __shared__ float posS[128];
    float* logitsS = (float*)region2;    // 64*80*4 = 20480 <= 33792

    const int tid  = threadIdx.x;
    const int wave = tid >> 6;
    const int lane = tid & 63;
    const int m0   = blockIdx.x * 64;

    if (tid < 128) posS[tid] = pos[m0 * 2 + tid];
    __syncthreads();

    // ---- layer 1 (2 -> 64), VALU; h1 stored [pt][dim] stride 72 ----
    #pragma unroll
    for (int r = 0; r < 8; ++r) {
        int idx = tid + r * 512;          // 64 pts x 64 dims
        int m = idx >> 6, n = idx & 63;
        float v = fmaf(posS[m * 2 + 0], w1[n], fmaf(posS[m * 2 + 1], w1[64 + n], b1[n]));
        region3[m * 72 + n] = f2bf(fmaxf(v, 0.0f));
    }
    __syncthreads();

    {   // L2: 64 -> 256
        f32x4 acc[2][4];
        mlp_layer< 64, 16, 2, 4,  2, 0, true, false, true, true, true>(
            acc, region3, 72, region1, 264, ws + P2_OFF, b2, wave, lane);
    }
    __syncthreads();

    {   // L4 accumulator lives across both halves
        f32x4 acc4[2][4];
        {   // L3a: h2 -> h3a (od 0..255)
            f32x4 acc[2][4];
            mlp_layer<256, 16, 2, 4,  8, 0, true, false, true, true, true>(
                acc, region1, 264, region2, 264, ws + P3_OFF, b3, wave, lane);
        }
        __syncthreads();
        // L4 part 1: k = 0..255 (h3a), bias-init, no store
        mlp_layer<256, 16, 2, 4, 16, 0, true, false, true, false, true>(
            acc4, region2, 264, region1, 264, ws + P4_OFF, b4, wave, lane);
        __syncthreads();
        {   // L3b: h2 -> h3b (od 256..511); no prefetch to cap VGPR w/ acc4 live
            f32x4 acc[2][4];
            mlp_layer<256, 16, 2, 4,  8, 0, true, false, true, true, false>(
                acc, region1, 264, region2, 264, ws + P3_OFF + (16 * 8 * 512), b3 + 256,
                wave, lane);
        }
        __syncthreads();
        // L4 part 2: k = 256..511 (h3b, local k 0..255; weight k-tiles 8..15), store h4
        mlp_layer<256, 16, 2, 4, 16, 8, true, false, false, true, true>(
            acc4, region2, 264, region1, 264, ws + P4_OFF, b4, wave, lane);
    }
    __syncthreads();

    {   // L5: 256 -> 64
        f32x4 acc[1][2];
        mlp_layer<256,  4, 1, 2,  8, 0, true, false, true, true, true>(
            acc, region1, 264, region3, 72, ws + P5_OFF, b5, wave, lane);
    }
    __syncthreads();

    {   // L6: 64 -> 80 logits (f32)
        f32x4 acc[1][4];
        mlp_layer< 64,  5, 1, 4,  2, 0, false, true, true, true, true>(
            acc, region3, 72, logitsS, 80, ws + P6_OFF,
            (const float*)(ws + B6_OFF), wave, lane);
    }
    __syncthreads();

    // ---- epilogue: softmax(75) + 5x5x3 gather + sigmoid, 8 lanes per point ----
    const int p = tid >> 3;              // point within tile
    const int s = tid & 7;               // sub-lane
    const float p0 = posS[p * 2 + 0], p1 = posS[p * 2 + 1];
    const int tx0 = (int)(p0 / PI_F * 1023.0f);                 // == int(gx), ix = tx0 + dy
    const int ty0 = (int)((p1 + PI_F) / TWO_PI_F * 2047.0f);    // == int(gy), iy = ty0 + dx

    const float* lrow = logitsS + p * 80;
    float lv[10];
    float mx = -1e30f;
    #pragma unroll
    for (int i = 0; i < 10; ++i) {
        int f = s + i * 8;
        float v = (f < 75) ? lrow[f] : -1e30f;
        lv[i] = v;
        mx = fmaxf(mx, v);
    }
    mx = fmaxf(mx, __shfl_xor(mx, 1, 8));
    mx = fmaxf(mx, __shfl_xor(mx, 2, 8));
    mx = fmaxf(mx, __shfl_xor(mx, 4, 8));

    float den = 0.0f, x0 = 0.0f, x1 = 0.0f, x2 = 0.0f;
    #pragma unroll
    for (int i = 0; i < 10; ++i) {
        int f = s + i * 8;
        if (f < 75) {
            float e = __expf(lv[i] - mx);
            den += e;
            int c = f / 25, rr = f % 25, dy = rr / 5, dx = rr % 5;
            float g = grid_pos[((tx0 + dy) * 2052 + (ty0 + dx)) * 3 + c];
            if      (c == 0) x0 += e * g;
            else if (c == 1) x1 += e * g;
            else             x2 += e * g;
        }
    }
    #pragma unroll
    for (int mask = 1; mask < 8; mask <<= 1) {
        den += __shfl_xor(den, mask, 8);
        x0  += __shfl_xor(x0,  mask, 8);
        x1  += __shfl_xor(x1,  mask, 8);
        x2  += __shfl_xor(x2,  mask, 8);
    }
    if (s < 3) {
        float xv = (s == 0) ? x0 : (s == 1 ? x1 : x2);
        xv /= den;
        float sig = 1.0f / (1.0f + __expf(-xv));
        out[(m0 + p) * 3 + s] = (sig > 0.1f) ? sig * 255.0f : 0.0f;
    }
}

extern "C" void kernel_launch(void* const* d_in, const int* in_sizes, int n_in,
                              void* d_out, int out_size, void* d_ws, size_t ws_size,
                              hipStream_t stream) {
    const float* pos      = (const float*)d_in[0];
    const float* grid_pos = (const float*)d_in[1];
    const float* w1 = (const float*)d_in[2];
    const float* b1 = (const float*)d_in[3];
    const float* w2 = (const float*)d_in[4];
    const float* b2 = (const float*)d_in[5];
    const float* w3 = (const float*)d_in[6];
    const float* b3 = (const float*)d_in[7];
    const float* w4 = (const float*)d_in[8];
    const float* b4 = (const float*)d_in[9];
    const float* w5 = (const float*)d_in[10];
    const float* b5 = (const float*)d_in[11];
    const float* w6 = (const float*)d_in[12];
    const float* b6 = (const float*)d_in[13];
    short* ws = (short*)d_ws;
    float* out = (float*)d_out;

    prep_weights<<<(PREP_TOTAL + 255) / 256, 256, 0, stream>>>(w2, w3, w4, w5, w6, b6, ws);
    gridnet_fused<<<262144 / 64, 512, 0, stream>>>(pos, grid_pos, w1, b1, b2, b3, b4, b5, ws, out);
}